// Round 8
// baseline (566.859 us; speedup 1.0000x reference)
//
#include <hip/hip_runtime.h>
#include <hip/hip_bf16.h>

// Problem constants
#define B_   8192
#define C_   1024
#define H_   16
#define M_   (B_ * 4)      // 32768 rows
#define K_   1024
#define N1_  3072          // qkv GEMM cols
// SCALE = 0.125 folded into W_qkvT q-section. fp8 weights pre-scaled x32,
// compensated by MX scale byte 122 (=2^-5).

typedef __attribute__((ext_vector_type(8))) short short8;
typedef __attribute__((ext_vector_type(4))) float f32x4;
typedef __attribute__((ext_vector_type(8))) int   int8v;

__device__ __forceinline__ unsigned short f2bf(float f) {
  union { float f; unsigned u; } v; v.f = f;
  unsigned r = v.u + 0x7fffu + ((v.u >> 16) & 1u);   // RNE
  return (unsigned short)(r >> 16);
}
__device__ __forceinline__ float bf2f(unsigned short u) {
  union { unsigned u; float f; } v; v.u = ((unsigned)u) << 16;
  return v.f;
}
__device__ __forceinline__ int pk_fp8(float a, float b, float c, float d) {
  int r = __builtin_amdgcn_cvt_pk_fp8_f32(a, b, 0, false);
  r = __builtin_amdgcn_cvt_pk_fp8_f32(c, d, r, true);
  return r;
}

// Fragment-packed operand layout (both GEMM operands). For row j, K-col c:
//   po = (j>>4)*16384 + (c>>7)*2048 + ((c>>4)&1)*1024 + ((c>>5)&3)*256
//        + (j&15)*16 + (c&15)
// so a wave's MFMA fragment load for (frag fi, k-half h) is ONE coalesced
// dwordx4 at  base + (row_grp+fi)*16384 + kt*2048 + h*1024 + lane*16.
__device__ __forceinline__ size_t bpack(int j, int c) {
  return (size_t)(j >> 4) * 16384 + (size_t)(c >> 7) * 2048 +
         (size_t)((c >> 4) & 1) * 1024 + (size_t)((c >> 5) & 3) * 256 +
         (size_t)(j & 15) * 16 + (size_t)(c & 15);
}

// ---- cast x: fp8 fragment-packed (GEMM1 A) + bf16 rows n in {1,2} for fixup --
// Block = one 16-row group (rg): its packed output is one contiguous 16 KB
// region. Thread (hl = t>>4 row-in-group, ck = t&15) handles 4 chunks of 16
// cols each; reads coalesced (64B/lane granule), writes full 64B lines.
__global__ __launch_bounds__(256) void cast_x_k(const float* __restrict__ x,
                                                unsigned char* __restrict__ x8,
                                                unsigned short* __restrict__ xsel) {
  const int rg = blockIdx.x;                // 2048 row-groups
  const int t = threadIdx.x;
  const int hl = t >> 4;                    // row within group
  const int ck = t & 15;                    // base chunk index
  const int row = rg * 16 + hl;
  const int n = row & 3;
  const float* xr = x + (size_t)row * 1024;
  unsigned char* og = x8 + (size_t)rg * 16384 + hl * 16;
  unsigned short* xr2 = (n == 1 || n == 2)
      ? xsel + ((size_t)(n - 1) * 8192 + (row >> 2)) * 1024 : nullptr;
#pragma unroll
  for (int i = 0; i < 4; ++i) {
    const int kk = ck + i * 16;             // chunk 0..63
    const int c = kk * 16;
    float4 v0 = *(const float4*)(xr + c);
    float4 v1 = *(const float4*)(xr + c + 4);
    float4 v2 = *(const float4*)(xr + c + 8);
    float4 v3 = *(const float4*)(xr + c + 12);
    int4 o;
    o.x = pk_fp8(v0.x, v0.y, v0.z, v0.w);
    o.y = pk_fp8(v1.x, v1.y, v1.z, v1.w);
    o.z = pk_fp8(v2.x, v2.y, v2.z, v2.w);
    o.w = pk_fp8(v3.x, v3.y, v3.z, v3.w);
    *(int4*)(og + (kk >> 3) * 2048 + (kk & 1) * 1024 + ((kk >> 1) & 3) * 256) = o;
    if (xr2) {
      ushort4 s0, s1, s2, s3;
      s0.x = f2bf(v0.x); s0.y = f2bf(v0.y); s0.z = f2bf(v0.z); s0.w = f2bf(v0.w);
      s1.x = f2bf(v1.x); s1.y = f2bf(v1.y); s1.z = f2bf(v1.z); s1.w = f2bf(v1.w);
      s2.x = f2bf(v2.x); s2.y = f2bf(v2.y); s2.z = f2bf(v2.z); s2.w = f2bf(v2.w);
      s3.x = f2bf(v3.x); s3.y = f2bf(v3.y); s3.z = f2bf(v3.z); s3.w = f2bf(v3.w);
      *(ushort4*)(xr2 + c) = s0;
      *(ushort4*)(xr2 + c + 4) = s1;
      *(ushort4*)(xr2 + c + 8) = s2;
      *(ushort4*)(xr2 + c + 12) = s3;
    }
  }
}

// ---- transpose W_qkv [1024,3072] -> [3072,1024]: bf16 (fixup B, row-major)
//      + fp8 x32 in fragment-packed layout for gemm_mx ------------------------
__global__ __launch_bounds__(256) void transpose_wqkv_k(const float* __restrict__ in,
                                                        unsigned short* __restrict__ outb,
                                                        unsigned char* __restrict__ out8) {
  __shared__ float t[32][33];
  int tx = threadIdx.x, ty = threadIdx.y;   // block (32,8)
  int j0 = blockIdx.x * 32, c0 = blockIdx.y * 32;
#pragma unroll
  for (int i = 0; i < 4; ++i)
    t[ty + i * 8][tx] = in[(size_t)(c0 + ty + i * 8) * N1_ + j0 + tx];
  __syncthreads();
#pragma unroll
  for (int i = 0; i < 4; ++i) {
    int j = j0 + ty + i * 8;
    int c = c0 + tx;
    float v = t[tx][ty + i * 8];
    if (j < 1024) v *= 0.125f;              // SCALE folded into q rows
    outb[(size_t)j * K_ + c] = f2bf(v);
    out8[bpack(j, c)] =
        (unsigned char)(__builtin_amdgcn_cvt_pk_fp8_f32(v * 32.f, v * 32.f, 0, false) & 0xff);
  }
}

// ---- cast W_proj -> fp8 x32, fragment-packed (NT GEMM uses W rows as-is) -----
__global__ __launch_bounds__(256) void cast_wproj_k(const float* __restrict__ in,
                                                    unsigned char* __restrict__ out) {
  int i = blockIdx.x * 256 + threadIdx.x;
  float4 v = ((const float4*)in)[i];
  int f = i * 4;                            // flat element index
  int j = f >> 10, c = f & 1023;            // row, col (c % 4 == 0)
  *(int*)(out + bpack(j, c)) = pk_fp8(v.x * 32.f, v.y * 32.f, v.z * 32.f, v.w * 32.f);
}

// ---- bf16 NT GEMM (m97 structure, round-0 verified) for attn_sel fixup ------
// A = xsel [16384,1024]; rows <8192 use Wq section, >=8192 use Wk section.
__global__ __launch_bounds__(256) void gemm_fixup(const unsigned short* __restrict__ A,
                                                  const unsigned short* __restrict__ B0,
                                                  unsigned short* __restrict__ Cbf) {
  __shared__ unsigned short lsA[128 * 32];
  __shared__ unsigned short lsB[128 * 32];
  const int K = 1024, Ncols = 1024;
  const int tid = threadIdx.x;
  const int wave = tid >> 6, lane = tid & 63;
  const int wm = (wave >> 1) * 64, wn = (wave & 1) * 64;
  const long tile_m = (long)blockIdx.y * 128, tile_n = (long)blockIdx.x * 128;
  const unsigned short* Bm = B0 + (tile_m >= 8192 ? (size_t)1024 * 1024 : 0);

  f32x4 acc[4][4] = {};
  const int ci0 = (wave * 2 + 0) * 64 + lane;
  const int ci1 = (wave * 2 + 1) * 64 + lane;
  const int r0 = ci0 >> 2, kc0 = (ci0 & 3) * 8;
  const int r1 = ci1 >> 2, kc1 = (ci1 & 3) * 8;
  const unsigned short* gA0 = A + (tile_m + r0) * K + kc0;
  const unsigned short* gA1 = A + (tile_m + r1) * K + kc1;
  const unsigned short* gB0 = Bm + (tile_n + r0) * K + kc0;
  const unsigned short* gB1 = Bm + (tile_n + r1) * K + kc1;
  unsigned short* dA0 = lsA + (wave * 2 + 0) * 512;
  unsigned short* dA1 = lsA + (wave * 2 + 1) * 512;
  unsigned short* dB0 = lsB + (wave * 2 + 0) * 512;
  unsigned short* dB1 = lsB + (wave * 2 + 1) * 512;
  const int r16 = lane & 15, q8 = (lane >> 4) * 8;

  for (int kt = 0; kt < K; kt += 32) {
    __builtin_amdgcn_global_load_lds((const __attribute__((address_space(1))) void*)(gA0 + kt),
                                     (__attribute__((address_space(3))) void*)dA0, 16, 0, 0);
    __builtin_amdgcn_global_load_lds((const __attribute__((address_space(1))) void*)(gA1 + kt),
                                     (__attribute__((address_space(3))) void*)dA1, 16, 0, 0);
    __builtin_amdgcn_global_load_lds((const __attribute__((address_space(1))) void*)(gB0 + kt),
                                     (__attribute__((address_space(3))) void*)dB0, 16, 0, 0);
    __builtin_amdgcn_global_load_lds((const __attribute__((address_space(1))) void*)(gB1 + kt),
                                     (__attribute__((address_space(3))) void*)dB1, 16, 0, 0);
    __syncthreads();
    short8 afr[4], bfr[4];
#pragma unroll
    for (int mi = 0; mi < 4; ++mi)
      afr[mi] = *(const short8*)&lsA[(wm + mi * 16 + r16) * 32 + q8];
#pragma unroll
    for (int ni = 0; ni < 4; ++ni)
      bfr[ni] = *(const short8*)&lsB[(wn + ni * 16 + r16) * 32 + q8];
#pragma unroll
    for (int mi = 0; mi < 4; ++mi)
#pragma unroll
      for (int ni = 0; ni < 4; ++ni)
        acc[mi][ni] = __builtin_amdgcn_mfma_f32_16x16x32_bf16(afr[mi], bfr[ni], acc[mi][ni], 0, 0, 0);
    __syncthreads();
  }
  const int cl = lane & 15, rq = (lane >> 4) * 4;
#pragma unroll
  for (int mi = 0; mi < 4; ++mi)
#pragma unroll
    for (int ni = 0; ni < 4; ++ni) {
      long col = tile_n + wn + ni * 16 + cl;
#pragma unroll
      for (int r = 0; r < 4; ++r) {
        long row = tile_m + wm + mi * 16 + rq + r;
        Cbf[(size_t)row * Ncols + col] = f2bf(acc[mi][ni][r]);
      }
    }
}

// ---- MX-fp8 NT GEMM, 128x128 tile, LDS-FREE (both operands direct) -----------
// C[m,n] = (2^(sA-127))(2^(sB-127)) sum_k A[m,k]B[n,k]
// Diagnosis r0-r7: every A-through-LDS design co-saturates the per-CU LDS pipe
// (stage writes + 2x-duplicated frag reads + conflicts ~ matrix-pipe cycles)
// -> MfmaUtil invariant at ~30% across 5 schedule variants. Fix: BOTH operands
// fragment-packed in memory (bpack); each wave loads its fragments as fully
// coalesced dwordx4 direct from L1/L2. No LDS, no barriers, no staging, no
// bank conflicts. Explicit register double-buffer gives a 1-iter lead; the
// compiler emits counted vmcnt(16) (never drains). Waves are fully independent
// streams: one wave's L2 latency hides under another's 553-cy MFMA block.
template <int OUTMODE>  // 0: bf16 C   1: fp32 C + bias
__global__ __launch_bounds__(256) void gemm_mx(const unsigned char* __restrict__ A,
                                               const unsigned char* __restrict__ Bm,
                                               unsigned short* __restrict__ Cbf,
                                               float* __restrict__ Cf,
                                               const float* __restrict__ bias,
                                               int Ncols, int sA, int sB) {
  const int tid = threadIdx.x;
  const int wave = tid >> 6, lane = tid & 63;
  const int wm = (wave >> 1) * 64, wn = (wave & 1) * 64;
  const int tile_m = blockIdx.y * 128, tile_n = blockIdx.x * 128;

  f32x4 acc[4][4] = {};
  const unsigned char* gA = A + (size_t)((tile_m + wm) >> 4) * 16384 + (size_t)lane * 16;
  const unsigned char* gB = Bm + (size_t)((tile_n + wn) >> 4) * 16384 + (size_t)lane * 16;

  int8v aP[4], bP[4], aQ[4], bQ[4];

  auto load8 = [&](const unsigned char* g, int t, int8v* dst) {
    const int kt16 = t * 2048;
#pragma unroll
    for (int i = 0; i < 4; ++i) {
      const unsigned char* p = g + (size_t)i * 16384 + kt16;
      int4 h0 = *(const int4*)p;            // k-half 0
      int4 h1 = *(const int4*)(p + 1024);   // k-half 1
      dst[i] = int8v{h0.x, h0.y, h0.z, h0.w, h1.x, h1.y, h1.z, h1.w};
    }
  };

  load8(gA, 0, aP);
  load8(gB, 0, bP);
#pragma unroll
  for (int t = 0; t < 8; ++t) {             // K=1024 hardcoded, fully unrolled
    const int8v* ca = (t & 1) ? aQ : aP;    // static select (t is compile-time)
    const int8v* cb = (t & 1) ? bQ : bP;
    int8v* na = (t & 1) ? aP : aQ;
    int8v* nb = (t & 1) ? bP : bQ;
    if (t + 1 < 8) { load8(gA, t + 1, na); load8(gB, t + 1, nb); }
    __builtin_amdgcn_s_setprio(1);
#pragma unroll
    for (int mi = 0; mi < 4; ++mi)
#pragma unroll
      for (int ni = 0; ni < 4; ++ni)
        acc[mi][ni] = __builtin_amdgcn_mfma_scale_f32_16x16x128_f8f6f4(
            ca[mi], cb[ni], acc[mi][ni], 0, 0, 0, sA, 0, sB);
    __builtin_amdgcn_s_setprio(0);
  }

  const int cl = lane & 15, rq = (lane >> 4) * 4;
#pragma unroll
  for (int mi = 0; mi < 4; ++mi)
#pragma unroll
    for (int ni = 0; ni < 4; ++ni) {
      long col = tile_n + wn + ni * 16 + cl;
      float bv = (OUTMODE == 1) ? bias[col] : 0.f;
#pragma unroll
      for (int r = 0; r < 4; ++r) {
        long row = tile_m + wm + mi * 16 + rq + r;
        if (OUTMODE == 0)
          Cbf[(size_t)row * Ncols + col] = f2bf(acc[mi][ni][r]);
        else
          Cf[(size_t)row * Ncols + col] = acc[mi][ni][r] + bv;
      }
    }
}

// ---- MFMA attention: 1 wave = 1 batch; attn_sel from accurate bf16 q1/k2 -----
__global__ __launch_bounds__(256) void attn_mfma_k(const unsigned short* __restrict__ qkv,
                                                   const unsigned short* __restrict__ q1,
                                                   const unsigned short* __restrict__ k2,
                                                   const float* __restrict__ WE,
                                                   const float* __restrict__ WF,
                                                   unsigned char* __restrict__ hmid8,
                                                   float* __restrict__ attn_sel) {
  __shared__ float As[4][16 * 17 + 2];
  const int tid = threadIdx.x;
  const int wave = tid >> 6, lane = tid & 63;
  const int b = blockIdx.x * 4 + wave;
  const size_t qb = (size_t)b * 4 * N1_;
  const int hl = lane & 15, qg = lane >> 4;

  // S[n][m] products (fp8-derived qkv: fine, softmax path is insensitive)
  f32x4 accS[4][4] = {};
  f32x4 accSel = {};
#pragma unroll
  for (int ch = 0; ch < 2; ++ch) {
    const int off = ch * 32 + qg * 8;
    short8 qf[4], kf[4];
#pragma unroll
    for (int n = 0; n < 4; ++n)
      qf[n] = *(const short8*)(qkv + qb + (size_t)n * N1_ + 0 + hl * 64 + off);
#pragma unroll
    for (int m = 0; m < 4; ++m)
      kf[m] = *(const short8*)(qkv + qb + (size_t)m * N1_ + 1024 + hl * 64 + off);
#pragma unroll
    for (int n = 0; n < 4; ++n)
#pragma unroll
      for (int m = 0; m < 4; ++m)
        accS[n][m] = __builtin_amdgcn_mfma_f32_16x16x32_bf16(qf[n], kf[m], accS[n][m], 0, 0, 0);
    // accurate attn_sel from bf16 fixup rows
    short8 qs = *(const short8*)(q1 + (size_t)b * 1024 + hl * 64 + off);
    short8 ks = *(const short8*)(k2 + (size_t)b * 1024 + hl * 64 + off);
    accSel = __builtin_amdgcn_mfma_f32_16x16x32_bf16(qs, ks, accSel, 0, 0, 0);
  }

#pragma unroll
  for (int r = 0; r < 4; ++r)
    attn_sel[(size_t)b * 256 + (qg * 4 + r) * 16 + hl] = 1.f / (1.f + __expf(-accSel[r]));

  if ((hl >> 2) == qg) {   // diagonal lanes: per-head softmax + A' = attn.WF
    const int h = hl, rr = h & 3;
    float Sm[4][4];
#pragma unroll
    for (int n = 0; n < 4; ++n)
#pragma unroll
      for (int m = 0; m < 4; ++m) Sm[n][m] = accS[n][m][rr];
#pragma unroll
    for (int n = 0; n < 4; ++n) {
      float lg[4];
#pragma unroll
      for (int p = 0; p < 4; ++p)
        lg[p] = Sm[n][0] * WE[p * 4] + Sm[n][1] * WE[p * 4 + 1] +
                Sm[n][2] * WE[p * 4 + 2] + Sm[n][3] * WE[p * 4 + 3];
      float mx = fmaxf(fmaxf(lg[0], lg[1]), fmaxf(lg[2], lg[3]));
      float e0 = __expf(lg[0] - mx), e1 = __expf(lg[1] - mx);
      float e2 = __expf(lg[2] - mx), e3 = __expf(lg[3] - mx);
      float inv = 1.f / (e0 + e1 + e2 + e3);
      e0 *= inv; e1 *= inv; e2 *= inv; e3 *= inv;
#pragma unroll
      for (int m = 0; m < 4; ++m)
        As[wave][h * 17 + n * 4 + m] =
            e0 * WF[0 * 4 + m] + e1 * WF[1 * 4 + m] + e2 * WF[2 * 4 + m] + e3 * WF[3 * 4 + m];
    }
  }
  __syncthreads();

  {  // out[h,n,d] = sum_m A'[n,m] v[h,m,d]; write hmid fp8 x32 fragment-packed
    const int h = lane & 15, dg = lane >> 4;
    float Ap[4][4];
#pragma unroll
    for (int n = 0; n < 4; ++n)
#pragma unroll
      for (int m = 0; m < 4; ++m) Ap[n][m] = As[wave][h * 17 + n * 4 + m];

    float outv[4][16] = {};
#pragma unroll
    for (int m = 0; m < 4; ++m) {
      const unsigned short* vp = qkv + qb + (size_t)m * N1_ + 2048 + h * 64 + dg * 16;
      short8 v0 = *(const short8*)(vp);
      short8 v1 = *(const short8*)(vp + 8);
      float vf[16];
#pragma unroll
      for (int j = 0; j < 8; ++j) {
        vf[j] = bf2f((unsigned short)v0[j]);
        vf[8 + j] = bf2f((unsigned short)v1[j]);
      }
#pragma unroll
      for (int n = 0; n < 4; ++n)
#pragma unroll
        for (int d = 0; d < 16; ++d) outv[n][d] += Ap[n][m] * vf[d];
    }
#pragma unroll
    for (int n = 0; n < 4; ++n) {
      int w0 = pk_fp8(outv[n][0] * 32.f, outv[n][1] * 32.f, outv[n][2] * 32.f, outv[n][3] * 32.f);
      int w1 = pk_fp8(outv[n][4] * 32.f, outv[n][5] * 32.f, outv[n][6] * 32.f, outv[n][7] * 32.f);
      int w2 = pk_fp8(outv[n][8] * 32.f, outv[n][9] * 32.f, outv[n][10] * 32.f, outv[n][11] * 32.f);
      int w3 = pk_fp8(outv[n][12] * 32.f, outv[n][13] * 32.f, outv[n][14] * 32.f, outv[n][15] * 32.f);
      *(int4*)(hmid8 + bpack(b * 4 + n, h * 64 + dg * 16)) = make_int4(w0, w1, w2, w3);
    }
  }
}

// ---- launch ------------------------------------------------------------------
extern "C" void kernel_launch(void* const* d_in, const int* in_sizes, int n_in,
                              void* d_out, int out_size, void* d_ws, size_t ws_size,
                              hipStream_t stream) {
  (void)in_sizes; (void)n_in; (void)out_size; (void)ws_size;
  const float* x      = (const float*)d_in[0];
  const float* W_qkv  = (const float*)d_in[1];
  const float* W_proj = (const float*)d_in[2];
  const float* b_proj = (const float*)d_in[3];
  const float* W_E    = (const float*)d_in[4];
  const float* W_F    = (const float*)d_in[5];

  float* out0 = (float*)d_out;                     // [B,N,C] fp32
  float* out1 = out0 + (size_t)M_ * C_;            // [B,H,H] fp32

  char* ws = (char*)d_ws;
  // Region 0 (201.3 MB): early = xsel(33.5M) + wqkvT_bf(6.3M); later = qkv_bf.
  unsigned short* xsel   = (unsigned short*)(ws);
  unsigned short* wqkvTb = (unsigned short*)(ws + 33554432);
  unsigned short* qkv_bf = (unsigned short*)(ws);               // overwrites after fixup
  unsigned char*  x8     = (unsigned char*)(ws + 201326592);    // 33.5M packed; hmid8 aliases
  unsigned char*  hmid8  = x8;
  unsigned char*  wqkvT8 = (unsigned char*)(ws + 234881024);    // 3.1M (fragment-packed)
  unsigned char*  wproj8 = (unsigned char*)(ws + 238026752);    // 1.0M (fragment-packed)
  unsigned short* q1k2   = (unsigned short*)(ws + 239075328);   // 33.5M (end 272.6M)

  cast_x_k<<<2048, 256, 0, stream>>>(x, x8, xsel);
  transpose_wqkv_k<<<dim3(96, 32), dim3(32, 8), 0, stream>>>(W_qkv, wqkvTb, wqkvT8);
  cast_wproj_k<<<1024, 256, 0, stream>>>(W_proj, wproj8);

  // accurate rows for attn_sel: q1 (rows 0..8191), k2 (rows 8192..16383)
  gemm_fixup<<<dim3(8, 128), 256, 0, stream>>>(xsel, wqkvTb, q1k2);

  // GEMM1: qkv = x @ W_qkv (MX-fp8; A scale 1.0, B x32 -> scale 122)
  gemm_mx<0><<<dim3(24, 256), 256, 0, stream>>>(x8, wqkvT8, qkv_bf, nullptr, nullptr,
                                                3072, 127, 122);

  attn_mfma_k<<<B_ / 4, 256, 0, stream>>>(qkv_bf, q1k2, q1k2 + (size_t)8192 * 1024,
                                          W_E, W_F, hmid8, out1);

  // GEMM2: out = hmid @ W_proj^T + b (both fp8 x32 -> scales 122,122)
  gemm_mx<1><<<dim3(8, 256), 256, 0, stream>>>(hmid8, wproj8, nullptr, out0, b_proj,
                                               1024, 122, 122);
}